// Round 6
// baseline (245.410 us; speedup 1.0000x reference)
//
#include <hip/hip_runtime.h>
#include <math.h>

// ---------------------------------------------------------------------------
// 2-layer GCN, commuted both layers, normalization folded into row scaling:
//   xs  = dinv .* f16(x)            (row-scaled features; zero row at index N)
//   h1  = relu((Σ_nbr xs)·wd @ W1 + b1)        } one fused MFMA kernel
//   h2s = dinv .* (h1 @ W2)                    }   (per-row wd = dinv[d])
//   out = wd·(Σ_nbr h2s) + b2
// Per-edge record is the 4-byte src index; tail slots point at zero row N.
// CSR build: two-level bucket sort (dst>>8) with LDS atomics; row scaling
// fused into k_bucket (each block owns its 256 nodes' dinv in LDS).
// Gather loops: 8-wide branch-free edge pipeline (16 row-loads in flight,
// one vmcnt drain per 8 edges), line-aligned 16B/lane row layout.
// NOTE: launch_bounds must stay loose on the gather kernels — (256,6)/(256,8)
// capped VGPRs to 40, spilled the edge pipeline (FETCH+WRITE +70MB scratch,
// +30us). (256,4) caps at 128 VGPR; 8-wide pipeline needs ~111.
// ---------------------------------------------------------------------------

#define RPB 32                      // node rows per fused block
#define CAP 8192                    // edge capacity per 256-dst bucket (avg ~3190)
#define PA_BLK 256                  // phase-A bucket blocks

typedef _Float16 h8  __attribute__((ext_vector_type(8)));
typedef _Float16 h2t __attribute__((ext_vector_type(2)));
typedef float    f4v __attribute__((ext_vector_type(4)));

__device__ __forceinline__ unsigned pkh(float a, float b) {
    auto r = __builtin_amdgcn_cvt_pkrtz(a, b);          // 2xf32 -> packed f16 (RTZ)
    return __builtin_bit_cast(unsigned, r);
}
__device__ __forceinline__ void accw(float* g, float c, unsigned w) {
    h2t p = __builtin_bit_cast(h2t, w);
    g[0] += c * (float)p.x;                             // v_fma_mix_f32
    g[1] += c * (float)p.y;
}
__device__ __forceinline__ void acc8h(float* ga, float c, uint4 u) {
    accw(ga + 0, c, u.x); accw(ga + 2, c, u.y);
    accw(ga + 4, c, u.z); accw(ga + 6, c, u.w);
}

// blocks [0,PA): bucket phase A (LDS hist + global reserve + scatter);
// [PA,PA+8): pack W1 MFMA B-frags; [+8,+12): pack W2 frags.
// B-frag layout (16x16x32): lane l, j=0..7 holds W[kt*32+(l>>4)*8+j][nt*16+(l&15)],
// stored at frag base ((kt*NT+nt)*64+l)*8 so a fragment load is one b128/lane.
__global__ __launch_bounds__(256) void k_prep(const int* __restrict__ src,
                                              const int* __restrict__ dst, int e,
                                              int* __restrict__ bcur,
                                              unsigned* __restrict__ ebuf, int EPB,
                                              const float* __restrict__ W1,
                                              const float* __restrict__ W2,
                                              unsigned short* __restrict__ Wpk1,
                                              unsigned short* __restrict__ Wpk2) {
    const int blk = (int)blockIdx.x;
    if (blk < PA_BLK) {
        __shared__ int h[256];          // per-bucket count, then local cursor
        __shared__ int gb[256];         // reserved global base per bucket
        const int t = threadIdx.x;
        h[t] = 0;
        __syncthreads();
        const int e0 = blk * EPB;
        const int e1 = min(e0 + EPB, e);
        for (int i = e0 + t; i < e1; i += 256)
            atomicAdd(&h[((unsigned)dst[i]) >> 8], 1);              // LDS
        __syncthreads();
        const int c = h[t];
        if (c > 0) gb[t] = atomicAdd(&bcur[t], c);                  // global reserve
        h[t] = 0;
        __syncthreads();
        for (int i = e0 + t; i < e1; i += 256) {
            const unsigned d  = (unsigned)dst[i];
            const int bk = d >> 8;
            const int p  = atomicAdd(&h[bk], 1) + gb[bk];           // LDS rank
            if (p < CAP) ebuf[((size_t)bk << 13) + p] = ((d & 255u) << 24) | (unsigned)src[i];
        }
    } else if (blk < PA_BLK + 8) {
        int idx = (blk - PA_BLK) * 256 + threadIdx.x;          // [0,2048)
        int l = idx & 63, g = idx >> 6;                        // g in [0,32)
        int kt = g >> 3, nt = g & 7;
        const float* Wp = W1 + (size_t)(kt * 32 + ((l >> 4) << 3)) * 128 + nt * 16 + (l & 15);
        uint4 o;
        o.x = pkh(Wp[0],   Wp[128]);
        o.y = pkh(Wp[256], Wp[384]);
        o.z = pkh(Wp[512], Wp[640]);
        o.w = pkh(Wp[768], Wp[896]);
        *(uint4*)&Wpk1[(size_t)idx * 8] = o;
    } else {
        int idx = (blk - PA_BLK - 8) * 256 + threadIdx.x;      // [0,1024)
        if (idx < 1024) {
            int l = idx & 63, g = idx >> 6;                    // g in [0,16)
            int kt = g >> 2, nt = g & 3;
            const float* Wp = W2 + (size_t)(kt * 32 + ((l >> 4) << 3)) * 64 + nt * 16 + (l & 15);
            uint4 o;
            o.x = pkh(Wp[0],   Wp[64]);
            o.y = pkh(Wp[128], Wp[192]);
            o.z = pkh(Wp[256], Wp[320]);
            o.w = pkh(Wp[384], Wp[448]);
            *(uint4*)&Wpk2[(size_t)idx * 8] = o;
        }
    }
}

// One block per 256-dst bucket: per-dst hist -> degrees/dinv/rowptr; scatter
// bucket edges (src only) to final dst-sorted erec positions; then scale this
// block's 256 rows: xs = dinv .* f16(x) (dinv from LDS, no global round-trip).
// Block 0 additionally zeroes pad row N of xs and h2s.
__global__ __launch_bounds__(256) void k_bucket(const unsigned* __restrict__ ebuf,
                                                const int* __restrict__ bcur,
                                                int* __restrict__ rowptr,
                                                float* __restrict__ dinv,
                                                unsigned* __restrict__ erec,
                                                const float* __restrict__ x,
                                                unsigned short* __restrict__ xs,
                                                unsigned short* __restrict__ h2s,
                                                int n, int nbk, int e) {
    __shared__ int sc[256];
    __shared__ int h[256];
    __shared__ int loc[256];
    __shared__ float sdinv[256];
    __shared__ int sBase;
    const int t = threadIdx.x;
    const int b = blockIdx.x;

    // bucket base = exclusive scan of (clamped) bucket totals at b
    const int v = (t < nbk) ? min(bcur[t], CAP) : 0;
    sc[t] = v;
    __syncthreads();
    for (int off = 1; off < 256; off <<= 1) {
        int u = (t >= off) ? sc[t - off] : 0;
        __syncthreads();
        sc[t] += u;
        __syncthreads();
    }
    if (t == b) sBase = sc[t] - v;
    if (b == 0 && t == 0) rowptr[n] = e;
    h[t] = 0;
    __syncthreads();

    const int cb = min(bcur[b], CAP);
    const unsigned* __restrict__ eb = ebuf + ((size_t)b << 13);
    for (int i = t; i < cb; i += 256) atomicAdd(&h[eb[i] >> 24], 1);
    __syncthreads();
    const int deg = h[t];
    sc[t] = deg;
    __syncthreads();
    for (int off = 1; off < 256; off <<= 1) {
        int u = (t >= off) ? sc[t - off] : 0;
        __syncthreads();
        sc[t] += u;
        __syncthreads();
    }
    loc[t] = sc[t] - deg;                  // local exclusive offset
    const int id = (b << 8) + t;
    float wdl = 0.f;
    if (id < n) {
        wdl = rsqrtf((float)(deg + 1));    // +1 self-loop
        rowptr[id] = sBase + loc[t];
        dinv[id]   = wdl;
    }
    sdinv[t] = wdl;
    h[t] = 0;                              // per-dst cursor
    __syncthreads();
    unsigned* __restrict__ outp = erec + sBase;
    for (int i = t; i < cb; i += 256) {
        const unsigned r  = eb[i];
        const int      lb = r >> 24;
        const int      p  = atomicAdd(&h[lb], 1);
        outp[loc[lb] + p] = r & 0xFFFFFFu;
    }

    // ---- fused row scaling for this block's nodes ----
    const int rbase = b << 8;
    const int nrow  = min(256, n - rbase);
#pragma unroll
    for (int k = 0; k < 16; ++k) {
        const int rr = (t >> 4) + k * 16;            // 0..255
        if (rr < nrow) {
            const float w = sdinv[rr];
            const size_t base8 = ((size_t)(rbase + rr)) * 128 + (t & 15) * 8;
            float4 v0 = *(const float4*)&x[base8];
            float4 v1 = *(const float4*)&x[base8 + 4];
            uint4 o;
            o.x = pkh(v0.x * w, v0.y * w); o.y = pkh(v0.z * w, v0.w * w);
            o.z = pkh(v1.x * w, v1.y * w); o.w = pkh(v1.z * w, v1.w * w);
            *(uint4*)&xs[base8] = o;
        }
    }
    if (b == 0) {                                    // zero pad row N
        if (t < 16)      *(uint4*)&xs [(size_t)n * 128 + t * 8]        = make_uint4(0, 0, 0, 0);
        else if (t < 24) *(uint4*)&h2s[(size_t)n * 64  + (t - 16) * 8] = make_uint4(0, 0, 0, 0);
    }
}

// ---------------------------------------------------------------------------
// Fused layer-1 + W2 commute.  32 rows/block, 256 thr (4 waves).
// Phase A: register gather, 8 lanes/row, lane b owns feats [8b,8b+8) and
//          [64+8b,64+8b+8) (one cache line per load instr per row); 8-wide
//          branch-free edge pipeline with record prefetch; uniform coef wd.
//          -> f16 into swizzled LDS sM[32][128].
// Phase B: MFMA (agg)@W1: wave w owns cols [32w,32w+32); A-frags from LDS
//          (b128, XOR-16 swizzle => conflict-free), B-frags from global Wpk1.
// Phase C: +b1, relu, write a1 back to the same LDS tile (f16, same swizzle).
// Phase D: MFMA a1@W2, scale by dinv[row] -> h2s (f16, (N+1) x 64) to global.
// LDS swizzle: byte ^= (row&7)<<4 applied to final address (write & read).
// ---------------------------------------------------------------------------
__global__ __launch_bounds__(256, 4) void fused_l1(const unsigned short* __restrict__ Xs,
                                                   const unsigned short* __restrict__ Wpk1,
                                                   const float* __restrict__ bias1,
                                                   const unsigned short* __restrict__ Wpk2,
                                                   const int* __restrict__ rowptr,
                                                   const unsigned* __restrict__ erec,
                                                   const float* __restrict__ dinv,
                                                   unsigned short* __restrict__ h2s,
                                                   int n) {
    __shared__ __align__(16) char sMb[RPB * 256];    // 32 rows x 128 f16 = 8 KB

    const int t    = threadIdx.x;
    const int row0 = blockIdx.x * RPB;

    // ---- Phase A: gather ----
    {
        const int r = t >> 3;                 // row-in-block 0..31
        const int b = t & 7;                  // lane-in-row  0..7 (16 feats each)
        const int d = row0 + r;
        float ga[16] = {};
        if (d < n) {
            const float wd = dinv[d];
            {
                const uint4* P = (const uint4*)(Xs + ((size_t)d << 7));
                uint4 sa = P[b];              // feats [8b, 8b+8)   (line 0)
                uint4 sb = P[8 + b];          // feats [64+8b, ..)  (line 1)
                acc8h(ga, wd, sa);
                acc8h(ga + 8, wd, sb);
            }
            const int beg = rowptr[d], end = rowptr[d + 1];
            int j = beg;
            const unsigned Z = (unsigned)n;   // zero row for tail slots
            if (j < end) {
                unsigned s[8];
#pragma unroll
                for (int q = 0; q < 8; ++q) s[q] = (j + q < end) ? erec[j + q] : Z;
                while (j < end) {
                    const int jn = j + 8;
                    uint4 rA[8], rB[8];
#pragma unroll
                    for (int q = 0; q < 8; ++q) {
                        const uint4* Pq = (const uint4*)(Xs + ((size_t)s[q] << 7));
                        rA[q] = Pq[b];
                        rB[q] = Pq[8 + b];
                    }
                    unsigned sn[8];
#pragma unroll
                    for (int q = 0; q < 8; ++q) sn[q] = (jn + q < end) ? erec[jn + q] : Z;
#pragma unroll
                    for (int q = 0; q < 8; ++q) {
                        acc8h(ga, wd, rA[q]);         // zero row kills tail slots
                        acc8h(ga + 8, wd, rB[q]);
                    }
#pragma unroll
                    for (int q = 0; q < 8; ++q) s[q] = sn[q];
                    j = jn;
                }
            }
        }
        uint4 o0, o1;
        o0.x = pkh(ga[0],  ga[1]);  o0.y = pkh(ga[2],  ga[3]);
        o0.z = pkh(ga[4],  ga[5]);  o0.w = pkh(ga[6],  ga[7]);
        o1.x = pkh(ga[8],  ga[9]);  o1.y = pkh(ga[10], ga[11]);
        o1.z = pkh(ga[12], ga[13]); o1.w = pkh(ga[14], ga[15]);
        const int swz = (r & 7) << 4;
        *(uint4*)(sMb + ((r * 256 + b * 16)       ^ swz)) = o0;   // feats 8b..
        *(uint4*)(sMb + ((r * 256 + 128 + b * 16) ^ swz)) = o1;   // feats 64+8b..
    }
    __syncthreads();

    const int w  = t >> 6;                    // wave 0..3
    const int l  = t & 63;
    const int lr = l & 15;                    // frag row/col within 16-tile
    const int lk = (l >> 4) << 4;             // byte offset of this lane's k-octet
    const int sz = (lr & 7) << 4;             // swizzle for rows lr and lr+16

    // ---- Phase B: agg@W1, wave w -> cols [32w, 32w+32) ----
    f4v acc[2][2] = {};
#pragma unroll
    for (int kt = 0; kt < 4; ++kt) {
        const int kb = kt * 64 + lk;
        h8 a0 = *(const h8*)(sMb + ((lr * 256 + kb)        ^ sz));
        h8 a1 = *(const h8*)(sMb + (((lr + 16) * 256 + kb) ^ sz));
        const h8* Bp = (const h8*)Wpk1 + (kt * 8 + w * 2) * 64 + l;
        h8 b0 = Bp[0];
        h8 b1 = Bp[64];
        acc[0][0] = __builtin_amdgcn_mfma_f32_16x16x32_f16(a0, b0, acc[0][0], 0, 0, 0);
        acc[0][1] = __builtin_amdgcn_mfma_f32_16x16x32_f16(a0, b1, acc[0][1], 0, 0, 0);
        acc[1][0] = __builtin_amdgcn_mfma_f32_16x16x32_f16(a1, b0, acc[1][0], 0, 0, 0);
        acc[1][1] = __builtin_amdgcn_mfma_f32_16x16x32_f16(a1, b1, acc[1][1], 0, 0, 0);
    }
    __syncthreads();                          // all sM reads done before a1 overwrite

    // ---- Phase C: bias+relu -> a1 (f16) back into the same LDS tile ----
    {
        const float bb0 = bias1[w * 32 + lr];
        const float bb1 = bias1[w * 32 + 16 + lr];
        const int c0 = (w * 32 + lr) * 2;
        const int c1 = (w * 32 + 16 + lr) * 2;
#pragma unroll
        for (int mt = 0; mt < 2; ++mt)
#pragma unroll
            for (int v = 0; v < 4; ++v) {
                const int row = mt * 16 + ((l >> 4) << 2) + v;
                const int rs  = (row & 7) << 4;
                float o0 = fmaxf(acc[mt][0][v] + bb0, 0.f);
                float o1 = fmaxf(acc[mt][1][v] + bb1, 0.f);
                *(_Float16*)(sMb + ((row * 256 + c0) ^ rs)) = (_Float16)o0;
                *(_Float16*)(sMb + ((row * 256 + c1) ^ rs)) = (_Float16)o1;
            }
    }
    __syncthreads();

    // ---- Phase D: a1@W2 -> h2s (scaled by dinv[row]), wave w -> cols [16w,16w+16) ----
    f4v acc2[2] = {};
#pragma unroll
    for (int kt = 0; kt < 4; ++kt) {
        const int kb = kt * 64 + lk;
        h8 a0 = *(const h8*)(sMb + ((lr * 256 + kb)        ^ sz));
        h8 a1 = *(const h8*)(sMb + (((lr + 16) * 256 + kb) ^ sz));
        h8 b  = *((const h8*)Wpk2 + (kt * 4 + w) * 64 + l);
        acc2[0] = __builtin_amdgcn_mfma_f32_16x16x32_f16(a0, b, acc2[0], 0, 0, 0);
        acc2[1] = __builtin_amdgcn_mfma_f32_16x16x32_f16(a1, b, acc2[1], 0, 0, 0);
    }
#pragma unroll
    for (int mt = 0; mt < 2; ++mt)
#pragma unroll
        for (int v = 0; v < 4; ++v) {
            const int row = row0 + mt * 16 + ((l >> 4) << 2) + v;
            if (row < n) {
                _Float16 hv = (_Float16)(acc2[mt][v] * dinv[row]);
                h2s[(size_t)row * 64 + w * 16 + lr] = __builtin_bit_cast(unsigned short, hv);
            }
        }
}

// ---------------------------------------------------------------------------
// Layer-2 aggregation: out[d] = wd*(h2s[d] + sum_e h2s[src_e]) + b2, wd=dinv[d].
// Pure 64-wide gather (128 B/row = 1 line): 8 lanes/row, 1 uint4 per lane;
// 8-wide edge pipeline with record prefetch.
// ---------------------------------------------------------------------------
__global__ __launch_bounds__(256, 6) void k_out(const unsigned short* __restrict__ h2s,
                                                const float* __restrict__ b2,
                                                const int* __restrict__ rowptr,
                                                const unsigned* __restrict__ erec,
                                                const float* __restrict__ dinv,
                                                float* __restrict__ out, int n) {
    const int t = threadIdx.x;
    const int r = t >> 3;
    const int b = t & 7;
    const int d = blockIdx.x * RPB + r;
    if (d >= n) return;

    const float wd = dinv[d];
    float ga[8] = {};
    {
        uint4 u = *((const uint4*)(h2s + ((size_t)d << 6)) + b);
        acc8h(ga, wd, u);                     // self term
    }
    const int beg = rowptr[d], end = rowptr[d + 1];
    int j = beg;
    const unsigned Z = (unsigned)n;
    if (j < end) {
        unsigned s[8];
#pragma unroll
        for (int q = 0; q < 8; ++q) s[q] = (j + q < end) ? erec[j + q] : Z;
        while (j < end) {
            const int jn = j + 8;
            uint4 u[8];
#pragma unroll
            for (int q = 0; q < 8; ++q)
                u[q] = *((const uint4*)(h2s + ((size_t)s[q] << 6)) + b);
            unsigned sn[8];
#pragma unroll
            for (int q = 0; q < 8; ++q) sn[q] = (jn + q < end) ? erec[jn + q] : Z;
#pragma unroll
            for (int q = 0; q < 8; ++q) acc8h(ga, wd, u[q]);
#pragma unroll
            for (int q = 0; q < 8; ++q) s[q] = sn[q];
            j = jn;
        }
    }
    const float4 bv0 = *(const float4*)&b2[b * 8];
    const float4 bv1 = *(const float4*)&b2[b * 8 + 4];
    float* O = out + (size_t)d * 64 + b * 8;
    *(float4*)O       = make_float4(ga[0] + bv0.x, ga[1] + bv0.y, ga[2] + bv0.z, ga[3] + bv0.w);
    *(float4*)(O + 4) = make_float4(ga[4] + bv1.x, ga[5] + bv1.y, ga[6] + bv1.z, ga[7] + bv1.w);
}

// ---------------------------------------------------------------------------

extern "C" void kernel_launch(void* const* d_in, const int* in_sizes, int n_in,
                              void* d_out, int out_size, void* d_ws, size_t ws_size,
                              hipStream_t stream) {
    const float* x  = (const float*)d_in[0];
    const int*   ei = (const int*)d_in[1];
    const float* W1 = (const float*)d_in[2];
    const float* b1 = (const float*)d_in[3];
    const float* W2 = (const float*)d_in[4];
    const float* b2 = (const float*)d_in[5];
    float* out = (float*)d_out;

    const int N = in_sizes[0] / 128;
    const int E = in_sizes[1] / 2;
    const int* src = ei;
    const int* dst = ei + E;
    const int NBK = (N + 255) >> 8;        // 196 for N=50000
    if (NBK > 256) return;                 // design limit (N <= 65536; src fits 24b)

    // workspace carve (256B aligned)
    size_t off = 0;
    char* base = (char*)d_ws;
    auto carve = [&](size_t bytes) -> void* {
        void* p = base + off;
        off += (bytes + 255) & ~(size_t)255;
        return p;
    };
    int*      bcur   = (int*)carve(256 * 4);               // zeroed per call
    int*      rowptr = (int*)carve((size_t)(N + 1) * 4);
    float*    dinv   = (float*)carve((size_t)N * 4);
    unsigned* erec   = (unsigned*)carve((size_t)E * 4);
    unsigned* ebuf   = (unsigned*)carve((size_t)256 * CAP * 4);  // bucket staging 8.4MB
    unsigned short* xs   = (unsigned short*)carve((size_t)(N + 1) * 128 * 2);
    unsigned short* h2s  = (unsigned short*)carve((size_t)(N + 1) * 64 * 2);
    unsigned short* Wpk1 = (unsigned short*)carve(128 * 128 * 2);
    unsigned short* Wpk2 = (unsigned short*)carve(128 * 64 * 2);

    if (off > ws_size) return;  // diagnostic guard

    // 1) bucket phase A + W frag-pack (one launch); per-bucket sort + row scale
    const int EPB = (E + PA_BLK - 1) / PA_BLK;
    hipMemsetAsync(bcur, 0, 256 * 4, stream);
    k_prep<<<PA_BLK + 12, 256, 0, stream>>>(src, dst, E, bcur, ebuf, EPB,
                                            W1, W2, Wpk1, Wpk2);
    k_bucket<<<NBK, 256, 0, stream>>>(ebuf, bcur, rowptr, dinv, erec,
                                      x, xs, h2s, N, NBK, E);

    const int nblk = (N + RPB - 1) / RPB;
    // 2) fused layer 1 (+W2 commute): h2s = dinv .* (relu(agg@W1 + b1) @ W2)
    fused_l1<<<nblk, 256, 0, stream>>>(xs, Wpk1, b1, Wpk2, rowptr, erec, dinv, h2s, N);
    // 3) layer 2 aggregation: out = wd*(agg h2s) + b2   (fp32 out)
    k_out<<<nblk, 256, 0, stream>>>(h2s, b2, rowptr, erec, dinv, out, N);
}

// Round 7
// 157.512 us; speedup vs baseline: 1.5580x; 1.5580x over previous
//
#include <hip/hip_runtime.h>
#include <math.h>

// ---------------------------------------------------------------------------
// 2-layer GCN, commuted both layers, normalization folded into row scaling:
//   xs  = dinv .* f16(x)            (row-scaled features; zero row at index N)
//   h1  = relu((Σ_nbr xs)·wd @ W1 + b1)        } one fused MFMA kernel
//   h2s = dinv .* (h1 @ W2)                    }   (per-row wd = dinv[d])
//   out = wd·(Σ_nbr h2s) + b2
// Per-edge record is the 4-byte src index; tail slots point at zero row N.
// CSR build: two-level bucket sort (dst>>8) with LDS atomics; row scaling
// fused into k_bucket (each block owns its 256 nodes' dinv in LDS).
// Gather loops: 4-wide branch-free edge pipeline (8 uint4 row-loads in
// flight).  EMPIRICAL REGISTER WALL (rounds 4+6): the allocator will not
// hold >8 in-flight uint4 temporaries — 8-wide (16 uint4) spilled to
// scratch (VGPR stuck at 64, WRITE_SIZE 13->179MB, fused_l1 35->98us)
// even under __launch_bounds__(256,4)'s 128-VGPR cap.  Tight bounds
// (256,6)/(256,8) also spilled (VGPR 40).  Keep 4-wide + (256,4)/(256,6).
// ---------------------------------------------------------------------------

#define RPB 32                      // node rows per fused block
#define CAP 8192                    // edge capacity per 256-dst bucket (avg ~3190)
#define PA_BLK 256                  // phase-A bucket blocks

typedef _Float16 h8  __attribute__((ext_vector_type(8)));
typedef _Float16 h2t __attribute__((ext_vector_type(2)));
typedef float    f4v __attribute__((ext_vector_type(4)));

__device__ __forceinline__ unsigned pkh(float a, float b) {
    auto r = __builtin_amdgcn_cvt_pkrtz(a, b);          // 2xf32 -> packed f16 (RTZ)
    return __builtin_bit_cast(unsigned, r);
}
__device__ __forceinline__ void accw(float* g, float c, unsigned w) {
    h2t p = __builtin_bit_cast(h2t, w);
    g[0] += c * (float)p.x;                             // v_fma_mix_f32
    g[1] += c * (float)p.y;
}
__device__ __forceinline__ void acc16h(float* ga, float c, uint4 u0, uint4 u1) {
    accw(ga + 0, c, u0.x); accw(ga + 2, c, u0.y);
    accw(ga + 4, c, u0.z); accw(ga + 6, c, u0.w);
    accw(ga + 8, c, u1.x); accw(ga + 10, c, u1.y);
    accw(ga + 12, c, u1.z); accw(ga + 14, c, u1.w);
}
__device__ __forceinline__ void acc8h(float* ga, float c, uint4 u) {
    accw(ga + 0, c, u.x); accw(ga + 2, c, u.y);
    accw(ga + 4, c, u.z); accw(ga + 6, c, u.w);
}

// blocks [0,PA): bucket phase A (LDS hist + global reserve + scatter);
// [PA,PA+8): pack W1 MFMA B-frags; [+8,+12): pack W2 frags.
// B-frag layout (16x16x32): lane l, j=0..7 holds W[kt*32+(l>>4)*8+j][nt*16+(l&15)],
// stored at frag base ((kt*NT+nt)*64+l)*8 so a fragment load is one b128/lane.
__global__ __launch_bounds__(256) void k_prep(const int* __restrict__ src,
                                              const int* __restrict__ dst, int e,
                                              int* __restrict__ bcur,
                                              unsigned* __restrict__ ebuf, int EPB,
                                              const float* __restrict__ W1,
                                              const float* __restrict__ W2,
                                              unsigned short* __restrict__ Wpk1,
                                              unsigned short* __restrict__ Wpk2) {
    const int blk = (int)blockIdx.x;
    if (blk < PA_BLK) {
        __shared__ int h[256];          // per-bucket count, then local cursor
        __shared__ int gb[256];         // reserved global base per bucket
        const int t = threadIdx.x;
        h[t] = 0;
        __syncthreads();
        const int e0 = blk * EPB;
        const int e1 = min(e0 + EPB, e);
        for (int i = e0 + t; i < e1; i += 256)
            atomicAdd(&h[((unsigned)dst[i]) >> 8], 1);              // LDS
        __syncthreads();
        const int c = h[t];
        if (c > 0) gb[t] = atomicAdd(&bcur[t], c);                  // global reserve
        h[t] = 0;
        __syncthreads();
        for (int i = e0 + t; i < e1; i += 256) {
            const unsigned d  = (unsigned)dst[i];
            const int bk = d >> 8;
            const int p  = atomicAdd(&h[bk], 1) + gb[bk];           // LDS rank
            if (p < CAP) ebuf[((size_t)bk << 13) + p] = ((d & 255u) << 24) | (unsigned)src[i];
        }
    } else if (blk < PA_BLK + 8) {
        int idx = (blk - PA_BLK) * 256 + threadIdx.x;          // [0,2048)
        int l = idx & 63, g = idx >> 6;                        // g in [0,32)
        int kt = g >> 3, nt = g & 7;
        const float* Wp = W1 + (size_t)(kt * 32 + ((l >> 4) << 3)) * 128 + nt * 16 + (l & 15);
        uint4 o;
        o.x = pkh(Wp[0],   Wp[128]);
        o.y = pkh(Wp[256], Wp[384]);
        o.z = pkh(Wp[512], Wp[640]);
        o.w = pkh(Wp[768], Wp[896]);
        *(uint4*)&Wpk1[(size_t)idx * 8] = o;
    } else {
        int idx = (blk - PA_BLK - 8) * 256 + threadIdx.x;      // [0,1024)
        if (idx < 1024) {
            int l = idx & 63, g = idx >> 6;                    // g in [0,16)
            int kt = g >> 2, nt = g & 3;
            const float* Wp = W2 + (size_t)(kt * 32 + ((l >> 4) << 3)) * 64 + nt * 16 + (l & 15);
            uint4 o;
            o.x = pkh(Wp[0],   Wp[64]);
            o.y = pkh(Wp[128], Wp[192]);
            o.z = pkh(Wp[256], Wp[320]);
            o.w = pkh(Wp[384], Wp[448]);
            *(uint4*)&Wpk2[(size_t)idx * 8] = o;
        }
    }
}

// One block per 256-dst bucket: per-dst hist -> degrees/dinv/rowptr; scatter
// bucket edges (src only) to final dst-sorted erec positions; then scale this
// block's 256 rows: xs = dinv .* f16(x) (dinv from LDS, no global round-trip).
// Block 0 additionally zeroes pad row N of xs and h2s.
__global__ __launch_bounds__(256) void k_bucket(const unsigned* __restrict__ ebuf,
                                                const int* __restrict__ bcur,
                                                int* __restrict__ rowptr,
                                                float* __restrict__ dinv,
                                                unsigned* __restrict__ erec,
                                                const float* __restrict__ x,
                                                unsigned short* __restrict__ xs,
                                                unsigned short* __restrict__ h2s,
                                                int n, int nbk, int e) {
    __shared__ int sc[256];
    __shared__ int h[256];
    __shared__ int loc[256];
    __shared__ float sdinv[256];
    __shared__ int sBase;
    const int t = threadIdx.x;
    const int b = blockIdx.x;

    // bucket base = exclusive scan of (clamped) bucket totals at b
    const int v = (t < nbk) ? min(bcur[t], CAP) : 0;
    sc[t] = v;
    __syncthreads();
    for (int off = 1; off < 256; off <<= 1) {
        int u = (t >= off) ? sc[t - off] : 0;
        __syncthreads();
        sc[t] += u;
        __syncthreads();
    }
    if (t == b) sBase = sc[t] - v;
    if (b == 0 && t == 0) rowptr[n] = e;
    h[t] = 0;
    __syncthreads();

    const int cb = min(bcur[b], CAP);
    const unsigned* __restrict__ eb = ebuf + ((size_t)b << 13);
    for (int i = t; i < cb; i += 256) atomicAdd(&h[eb[i] >> 24], 1);
    __syncthreads();
    const int deg = h[t];
    sc[t] = deg;
    __syncthreads();
    for (int off = 1; off < 256; off <<= 1) {
        int u = (t >= off) ? sc[t - off] : 0;
        __syncthreads();
        sc[t] += u;
        __syncthreads();
    }
    loc[t] = sc[t] - deg;                  // local exclusive offset
    const int id = (b << 8) + t;
    float wdl = 0.f;
    if (id < n) {
        wdl = rsqrtf((float)(deg + 1));    // +1 self-loop
        rowptr[id] = sBase + loc[t];
        dinv[id]   = wdl;
    }
    sdinv[t] = wdl;
    h[t] = 0;                              // per-dst cursor
    __syncthreads();
    unsigned* __restrict__ outp = erec + sBase;
    for (int i = t; i < cb; i += 256) {
        const unsigned r  = eb[i];
        const int      lb = r >> 24;
        const int      p  = atomicAdd(&h[lb], 1);
        outp[loc[lb] + p] = r & 0xFFFFFFu;
    }

    // ---- fused row scaling for this block's nodes ----
    const int rbase = b << 8;
    const int nrow  = min(256, n - rbase);
#pragma unroll
    for (int k = 0; k < 16; ++k) {
        const int rr = (t >> 4) + k * 16;            // 0..255
        if (rr < nrow) {
            const float w = sdinv[rr];
            const size_t base8 = ((size_t)(rbase + rr)) * 128 + (t & 15) * 8;
            float4 v0 = *(const float4*)&x[base8];
            float4 v1 = *(const float4*)&x[base8 + 4];
            uint4 o;
            o.x = pkh(v0.x * w, v0.y * w); o.y = pkh(v0.z * w, v0.w * w);
            o.z = pkh(v1.x * w, v1.y * w); o.w = pkh(v1.z * w, v1.w * w);
            *(uint4*)&xs[base8] = o;
        }
    }
    if (b == 0) {                                    // zero pad row N
        if (t < 16)      *(uint4*)&xs [(size_t)n * 128 + t * 8]        = make_uint4(0, 0, 0, 0);
        else if (t < 24) *(uint4*)&h2s[(size_t)n * 64  + (t - 16) * 8] = make_uint4(0, 0, 0, 0);
    }
}

// ---------------------------------------------------------------------------
// Fused layer-1 + W2 commute.  32 rows/block, 256 thr (4 waves).
// Phase A: register gather (8 lanes/row, 16 f16 feats/lane, 4-wide branch-free
//          edge pipeline, uniform coef wd) -> f16 into swizzled LDS sM[32][128].
// Phase B: MFMA (agg)@W1: wave w owns cols [32w,32w+32); A-frags from LDS
//          (b128, XOR-16 swizzle => conflict-free), B-frags from global Wpk1.
// Phase C: +b1, relu, write a1 back to the same LDS tile (f16, same swizzle).
// Phase D: MFMA a1@W2, scale by dinv[row] -> h2s (f16, (N+1) x 64) to global.
// LDS swizzle: byte ^= (row&7)<<4 applied to final address (write & read).
// ---------------------------------------------------------------------------
__global__ __launch_bounds__(256, 4) void fused_l1(const unsigned short* __restrict__ Xs,
                                                   const unsigned short* __restrict__ Wpk1,
                                                   const float* __restrict__ bias1,
                                                   const unsigned short* __restrict__ Wpk2,
                                                   const int* __restrict__ rowptr,
                                                   const unsigned* __restrict__ erec,
                                                   const float* __restrict__ dinv,
                                                   unsigned short* __restrict__ h2s,
                                                   int n) {
    __shared__ __align__(16) char sMb[RPB * 256];    // 32 rows x 128 f16 = 8 KB

    const int t    = threadIdx.x;
    const int row0 = blockIdx.x * RPB;

    // ---- Phase A: gather ----
    {
        const int r = t >> 3;                 // row-in-block 0..31
        const int b = t & 7;                  // lane-in-row  0..7 (16 feats each)
        const int d = row0 + r;
        float ga[16] = {};
        if (d < n) {
            const float wd = dinv[d];
            const uint4* P = (const uint4*)(Xs + ((size_t)d << 7)) + b * 2;
            acc16h(ga, wd, P[0], P[1]);       // self term: wd*xs[d] = wd^2*x[d]
            const int beg = rowptr[d], end = rowptr[d + 1];
            int j = beg;
            const unsigned Z = (unsigned)n;   // zero row for tail slots
            unsigned s0 = (j     < end) ? erec[j]     : Z;
            unsigned s1 = (j + 1 < end) ? erec[j + 1] : Z;
            unsigned s2 = (j + 2 < end) ? erec[j + 2] : Z;
            unsigned s3 = (j + 3 < end) ? erec[j + 3] : Z;
            while (j < end) {
                const unsigned c0 = s0, c1 = s1, c2 = s2, c3 = s3;
                const int jn = j + 4;
                s0 = (jn     < end) ? erec[jn]     : Z;   // prefetch next quad
                s1 = (jn + 1 < end) ? erec[jn + 1] : Z;
                s2 = (jn + 2 < end) ? erec[jn + 2] : Z;
                s3 = (jn + 3 < end) ? erec[jn + 3] : Z;
                const uint4* P0 = (const uint4*)(Xs + ((size_t)c0 << 7)) + b * 2;
                const uint4* P1 = (const uint4*)(Xs + ((size_t)c1 << 7)) + b * 2;
                const uint4* P2 = (const uint4*)(Xs + ((size_t)c2 << 7)) + b * 2;
                const uint4* P3 = (const uint4*)(Xs + ((size_t)c3 << 7)) + b * 2;
                uint4 a0 = P0[0], a1 = P0[1];
                uint4 b0 = P1[0], b1 = P1[1];
                uint4 d0 = P2[0], d1 = P2[1];
                uint4 e0 = P3[0], e1 = P3[1];
                acc16h(ga, wd, a0, a1);       // uniform coef; zero row kills tail
                acc16h(ga, wd, b0, b1);
                acc16h(ga, wd, d0, d1);
                acc16h(ga, wd, e0, e1);
                j = jn;
            }
        }
        uint4 o0, o1;
        o0.x = pkh(ga[0],  ga[1]);  o0.y = pkh(ga[2],  ga[3]);
        o0.z = pkh(ga[4],  ga[5]);  o0.w = pkh(ga[6],  ga[7]);
        o1.x = pkh(ga[8],  ga[9]);  o1.y = pkh(ga[10], ga[11]);
        o1.z = pkh(ga[12], ga[13]); o1.w = pkh(ga[14], ga[15]);
        const int swz = (r & 7) << 4;
        *(uint4*)(sMb + ((r * 256 + b * 32)      ^ swz)) = o0;
        *(uint4*)(sMb + ((r * 256 + b * 32 + 16) ^ swz)) = o1;
    }
    __syncthreads();

    const int w  = t >> 6;                    // wave 0..3
    const int l  = t & 63;
    const int lr = l & 15;                    // frag row/col within 16-tile
    const int lk = (l >> 4) << 4;             // byte offset of this lane's k-octet
    const int sz = (lr & 7) << 4;             // swizzle for rows lr and lr+16

    // ---- Phase B: agg@W1, wave w -> cols [32w, 32w+32) ----
    f4v acc[2][2] = {};
#pragma unroll
    for (int kt = 0; kt < 4; ++kt) {
        const int kb = kt * 64 + lk;
        h8 a0 = *(const h8*)(sMb + ((lr * 256 + kb)        ^ sz));
        h8 a1 = *(const h8*)(sMb + (((lr + 16) * 256 + kb) ^ sz));
        const h8* Bp = (const h8*)Wpk1 + (kt * 8 + w * 2) * 64 + l;
        h8 b0 = Bp[0];
        h8 b1 = Bp[64];
        acc[0][0] = __builtin_amdgcn_mfma_f32_16x16x32_f16(a0, b0, acc[0][0], 0, 0, 0);
        acc[0][1] = __builtin_amdgcn_mfma_f32_16x16x32_f16(a0, b1, acc[0][1], 0, 0, 0);
        acc[1][0] = __builtin_amdgcn_mfma_f32_16x16x32_f16(a1, b0, acc[1][0], 0, 0, 0);
        acc[1][1] = __builtin_amdgcn_mfma_f32_16x16x32_f16(a1, b1, acc[1][1], 0, 0, 0);
    }
    __syncthreads();                          // all sM reads done before a1 overwrite

    // ---- Phase C: bias+relu -> a1 (f16) back into the same LDS tile ----
    {
        const float bb0 = bias1[w * 32 + lr];
        const float bb1 = bias1[w * 32 + 16 + lr];
        const int c0 = (w * 32 + lr) * 2;
        const int c1 = (w * 32 + 16 + lr) * 2;
#pragma unroll
        for (int mt = 0; mt < 2; ++mt)
#pragma unroll
            for (int v = 0; v < 4; ++v) {
                const int row = mt * 16 + ((l >> 4) << 2) + v;
                const int rs  = (row & 7) << 4;
                float o0 = fmaxf(acc[mt][0][v] + bb0, 0.f);
                float o1 = fmaxf(acc[mt][1][v] + bb1, 0.f);
                *(_Float16*)(sMb + ((row * 256 + c0) ^ rs)) = (_Float16)o0;
                *(_Float16*)(sMb + ((row * 256 + c1) ^ rs)) = (_Float16)o1;
            }
    }
    __syncthreads();

    // ---- Phase D: a1@W2 -> h2s (scaled by dinv[row]), wave w -> cols [16w,16w+16) ----
    f4v acc2[2] = {};
#pragma unroll
    for (int kt = 0; kt < 4; ++kt) {
        const int kb = kt * 64 + lk;
        h8 a0 = *(const h8*)(sMb + ((lr * 256 + kb)        ^ sz));
        h8 a1 = *(const h8*)(sMb + (((lr + 16) * 256 + kb) ^ sz));
        h8 b  = *((const h8*)Wpk2 + (kt * 4 + w) * 64 + l);
        acc2[0] = __builtin_amdgcn_mfma_f32_16x16x32_f16(a0, b, acc2[0], 0, 0, 0);
        acc2[1] = __builtin_amdgcn_mfma_f32_16x16x32_f16(a1, b, acc2[1], 0, 0, 0);
    }
#pragma unroll
    for (int mt = 0; mt < 2; ++mt)
#pragma unroll
        for (int v = 0; v < 4; ++v) {
            const int row = row0 + mt * 16 + ((l >> 4) << 2) + v;
            if (row < n) {
                _Float16 hv = (_Float16)(acc2[mt][v] * dinv[row]);
                h2s[(size_t)row * 64 + w * 16 + lr] = __builtin_bit_cast(unsigned short, hv);
            }
        }
}

// ---------------------------------------------------------------------------
// Layer-2 aggregation: out[d] = wd*(h2s[d] + sum_e h2s[src_e]) + b2, wd=dinv[d].
// Pure 64-wide gather (128 B/row): 8 lanes/row, 1 uint4 (8 f16) per lane;
// 4-wide edge pipeline with record prefetch.
// ---------------------------------------------------------------------------
__global__ __launch_bounds__(256, 6) void k_out(const unsigned short* __restrict__ h2s,
                                                const float* __restrict__ b2,
                                                const int* __restrict__ rowptr,
                                                const unsigned* __restrict__ erec,
                                                const float* __restrict__ dinv,
                                                float* __restrict__ out, int n) {
    const int t = threadIdx.x;
    const int r = t >> 3;
    const int b = t & 7;
    const int d = blockIdx.x * RPB + r;
    if (d >= n) return;

    const float wd = dinv[d];
    float ga[8] = {};
    {
        uint4 u = *((const uint4*)(h2s + ((size_t)d << 6)) + b);
        acc8h(ga, wd, u);                     // self term
    }
    const int beg = rowptr[d], end = rowptr[d + 1];
    int j = beg;
    const unsigned Z = (unsigned)n;
    unsigned s0 = (j     < end) ? erec[j]     : Z;
    unsigned s1 = (j + 1 < end) ? erec[j + 1] : Z;
    unsigned s2 = (j + 2 < end) ? erec[j + 2] : Z;
    unsigned s3 = (j + 3 < end) ? erec[j + 3] : Z;
    while (j < end) {
        const unsigned c0 = s0, c1 = s1, c2 = s2, c3 = s3;
        const int jn = j + 4;
        s0 = (jn     < end) ? erec[jn]     : Z;
        s1 = (jn + 1 < end) ? erec[jn + 1] : Z;
        s2 = (jn + 2 < end) ? erec[jn + 2] : Z;
        s3 = (jn + 3 < end) ? erec[jn + 3] : Z;
        uint4 u0 = *((const uint4*)(h2s + ((size_t)c0 << 6)) + b);
        uint4 u1 = *((const uint4*)(h2s + ((size_t)c1 << 6)) + b);
        uint4 u2 = *((const uint4*)(h2s + ((size_t)c2 << 6)) + b);
        uint4 u3 = *((const uint4*)(h2s + ((size_t)c3 << 6)) + b);
        acc8h(ga, wd, u0);
        acc8h(ga, wd, u1);
        acc8h(ga, wd, u2);
        acc8h(ga, wd, u3);
        j = jn;
    }
    const float4 bv0 = *(const float4*)&b2[b * 8];
    const float4 bv1 = *(const float4*)&b2[b * 8 + 4];
    float* O = out + (size_t)d * 64 + b * 8;
    *(float4*)O       = make_float4(ga[0] + bv0.x, ga[1] + bv0.y, ga[2] + bv0.z, ga[3] + bv0.w);
    *(float4*)(O + 4) = make_float4(ga[4] + bv1.x, ga[5] + bv1.y, ga[6] + bv1.z, ga[7] + bv1.w);
}

// ---------------------------------------------------------------------------

extern "C" void kernel_launch(void* const* d_in, const int* in_sizes, int n_in,
                              void* d_out, int out_size, void* d_ws, size_t ws_size,
                              hipStream_t stream) {
    const float* x  = (const float*)d_in[0];
    const int*   ei = (const int*)d_in[1];
    const float* W1 = (const float*)d_in[2];
    const float* b1 = (const float*)d_in[3];
    const float* W2 = (const float*)d_in[4];
    const float* b2 = (const float*)d_in[5];
    float* out = (float*)d_out;

    const int N = in_sizes[0] / 128;
    const int E = in_sizes[1] / 2;
    const int* src = ei;
    const int* dst = ei + E;
    const int NBK = (N + 255) >> 8;        // 196 for N=50000
    if (NBK > 256) return;                 // design limit (N <= 65536; src fits 24b)

    // workspace carve (256B aligned)
    size_t off = 0;
    char* base = (char*)d_ws;
    auto carve = [&](size_t bytes) -> void* {
        void* p = base + off;
        off += (bytes + 255) & ~(size_t)255;
        return p;
    };
    int*      bcur   = (int*)carve(256 * 4);               // zeroed per call
    int*      rowptr = (int*)carve((size_t)(N + 1) * 4);
    float*    dinv   = (float*)carve((size_t)N * 4);
    unsigned* erec   = (unsigned*)carve((size_t)E * 4);
    unsigned* ebuf   = (unsigned*)carve((size_t)256 * CAP * 4);  // bucket staging 8.4MB
    unsigned short* xs   = (unsigned short*)carve((size_t)(N + 1) * 128 * 2);
    unsigned short* h2s  = (unsigned short*)carve((size_t)(N + 1) * 64 * 2);
    unsigned short* Wpk1 = (unsigned short*)carve(128 * 128 * 2);
    unsigned short* Wpk2 = (unsigned short*)carve(128 * 64 * 2);

    if (off > ws_size) return;  // diagnostic guard

    // 1) bucket phase A + W frag-pack (one launch); per-bucket sort + row scale
    const int EPB = (E + PA_BLK - 1) / PA_BLK;
    hipMemsetAsync(bcur, 0, 256 * 4, stream);
    k_prep<<<PA_BLK + 12, 256, 0, stream>>>(src, dst, E, bcur, ebuf, EPB,
                                            W1, W2, Wpk1, Wpk2);
    k_bucket<<<NBK, 256, 0, stream>>>(ebuf, bcur, rowptr, dinv, erec,
                                      x, xs, h2s, N, NBK, E);

    const int nblk = (N + RPB - 1) / RPB;
    // 2) fused layer 1 (+W2 commute): h2s = dinv .* (relu(agg@W1 + b1) @ W2)
    fused_l1<<<nblk, 256, 0, stream>>>(xs, Wpk1, b1, Wpk2, rowptr, erec, dinv, h2s, N);
    // 3) layer 2 aggregation: out = wd*(agg h2s) + b2   (fp32 out)
    k_out<<<nblk, 256, 0, stream>>>(h2s, b2, rowptr, erec, dinv, out, N);
}

// Round 8
// 148.704 us; speedup vs baseline: 1.6503x; 1.0592x over previous
//
#include <hip/hip_runtime.h>
#include <math.h>

// ---------------------------------------------------------------------------
// 2-layer GCN, commuted both layers, normalization folded into row scaling:
//   xs  = dinv .* f16(x)            (row-scaled features; zero row at index N)
//   h1  = relu((Σ_nbr xs)·wd @ W1 + b1)        } one fused MFMA kernel
//   h2s = dinv .* (h1 @ W2)                    }   (per-row wd = dinv[d])
//   out = wd·(Σ_nbr h2s) + b2
// Per-edge record is the 4-byte src index; tail slots point at zero row N.
// CSR build: two-level bucket sort (dst>>8) with LDS atomics. k_scale is a
// SEPARATE kernel (fusing it into 196-block k_bucket under-parallelizes).
//
// EMPIRICAL REGISTER WALL (rounds 4/6): allocator holds at most 8 in-flight
// uint4 temporaries, and ONLY as named scalars (arrays spill to scratch even
// under a 128-VGPR cap; tight launch_bounds also spill).  This round: 16
// lanes/row x 16B => 1 uint4 per edge => DEPTH-8 pipeline within the same
// 8-register budget (was depth-4 x 2 uint4).  fused_l1 RPB=16, k_out depth-8.
// ---------------------------------------------------------------------------

#define RPB1 16                     // node rows per fused_l1 block
#define RPBO 32                     // node rows per k_out block
#define CAP 8192                    // edge capacity per 256-dst bucket (avg ~3190)
#define PA_BLK 256                  // phase-A bucket blocks

typedef _Float16 h8  __attribute__((ext_vector_type(8)));
typedef _Float16 h2t __attribute__((ext_vector_type(2)));
typedef float    f4v __attribute__((ext_vector_type(4)));

__device__ __forceinline__ unsigned pkh(float a, float b) {
    auto r = __builtin_amdgcn_cvt_pkrtz(a, b);          // 2xf32 -> packed f16 (RTZ)
    return __builtin_bit_cast(unsigned, r);
}
__device__ __forceinline__ void accw(float* g, float c, unsigned w) {
    h2t p = __builtin_bit_cast(h2t, w);
    g[0] += c * (float)p.x;                             // v_fma_mix_f32
    g[1] += c * (float)p.y;
}
__device__ __forceinline__ void acc8h(float* ga, float c, uint4 u) {
    accw(ga + 0, c, u.x); accw(ga + 2, c, u.y);
    accw(ga + 4, c, u.z); accw(ga + 6, c, u.w);
}

// blocks [0,PA): bucket phase A (LDS hist + global reserve + scatter);
// [PA,PA+8): pack W1 MFMA B-frags; [+8,+12): pack W2 frags.
// B-frag layout (16x16x32): lane l, j=0..7 holds W[kt*32+(l>>4)*8+j][nt*16+(l&15)],
// stored at frag base ((kt*NT+nt)*64+l)*8 so a fragment load is one b128/lane.
__global__ __launch_bounds__(256) void k_prep(const int* __restrict__ src,
                                              const int* __restrict__ dst, int e,
                                              int* __restrict__ bcur,
                                              unsigned* __restrict__ ebuf, int EPB,
                                              const float* __restrict__ W1,
                                              const float* __restrict__ W2,
                                              unsigned short* __restrict__ Wpk1,
                                              unsigned short* __restrict__ Wpk2) {
    const int blk = (int)blockIdx.x;
    if (blk < PA_BLK) {
        __shared__ int h[256];          // per-bucket count, then local cursor
        __shared__ int gb[256];         // reserved global base per bucket
        const int t = threadIdx.x;
        h[t] = 0;
        __syncthreads();
        const int e0 = blk * EPB;
        const int e1 = min(e0 + EPB, e);
        for (int i = e0 + t; i < e1; i += 256)
            atomicAdd(&h[((unsigned)dst[i]) >> 8], 1);              // LDS
        __syncthreads();
        const int c = h[t];
        if (c > 0) gb[t] = atomicAdd(&bcur[t], c);                  // global reserve
        h[t] = 0;
        __syncthreads();
        for (int i = e0 + t; i < e1; i += 256) {
            const unsigned d  = (unsigned)dst[i];
            const int bk = d >> 8;
            const int p  = atomicAdd(&h[bk], 1) + gb[bk];           // LDS rank
            if (p < CAP) ebuf[((size_t)bk << 13) + p] = ((d & 255u) << 24) | (unsigned)src[i];
        }
    } else if (blk < PA_BLK + 8) {
        int idx = (blk - PA_BLK) * 256 + threadIdx.x;          // [0,2048)
        int l = idx & 63, g = idx >> 6;                        // g in [0,32)
        int kt = g >> 3, nt = g & 7;
        const float* Wp = W1 + (size_t)(kt * 32 + ((l >> 4) << 3)) * 128 + nt * 16 + (l & 15);
        uint4 o;
        o.x = pkh(Wp[0],   Wp[128]);
        o.y = pkh(Wp[256], Wp[384]);
        o.z = pkh(Wp[512], Wp[640]);
        o.w = pkh(Wp[768], Wp[896]);
        *(uint4*)&Wpk1[(size_t)idx * 8] = o;
    } else {
        int idx = (blk - PA_BLK - 8) * 256 + threadIdx.x;      // [0,1024)
        if (idx < 1024) {
            int l = idx & 63, g = idx >> 6;                    // g in [0,16)
            int kt = g >> 2, nt = g & 3;
            const float* Wp = W2 + (size_t)(kt * 32 + ((l >> 4) << 3)) * 64 + nt * 16 + (l & 15);
            uint4 o;
            o.x = pkh(Wp[0],   Wp[64]);
            o.y = pkh(Wp[128], Wp[192]);
            o.z = pkh(Wp[256], Wp[320]);
            o.w = pkh(Wp[384], Wp[448]);
            *(uint4*)&Wpk2[(size_t)idx * 8] = o;
        }
    }
}

// One block per 256-dst bucket: per-dst hist -> degrees/dinv/rowptr; scatter
// bucket edges (src only) to final dst-sorted erec positions.
__global__ __launch_bounds__(256) void k_bucket(const unsigned* __restrict__ ebuf,
                                                const int* __restrict__ bcur,
                                                int* __restrict__ rowptr,
                                                float* __restrict__ dinv,
                                                unsigned* __restrict__ erec,
                                                int n, int nbk, int e) {
    __shared__ int sc[256];
    __shared__ int h[256];
    __shared__ int loc[256];
    __shared__ int sBase;
    const int t = threadIdx.x;
    const int b = blockIdx.x;

    // bucket base = exclusive scan of (clamped) bucket totals at b
    const int v = (t < nbk) ? min(bcur[t], CAP) : 0;
    sc[t] = v;
    __syncthreads();
    for (int off = 1; off < 256; off <<= 1) {
        int u = (t >= off) ? sc[t - off] : 0;
        __syncthreads();
        sc[t] += u;
        __syncthreads();
    }
    if (t == b) sBase = sc[t] - v;
    if (b == 0 && t == 0) rowptr[n] = e;
    h[t] = 0;
    __syncthreads();

    const int cb = min(bcur[b], CAP);
    const unsigned* __restrict__ eb = ebuf + ((size_t)b << 13);
    for (int i = t; i < cb; i += 256) atomicAdd(&h[eb[i] >> 24], 1);
    __syncthreads();
    const int deg = h[t];
    sc[t] = deg;
    __syncthreads();
    for (int off = 1; off < 256; off <<= 1) {
        int u = (t >= off) ? sc[t - off] : 0;
        __syncthreads();
        sc[t] += u;
        __syncthreads();
    }
    loc[t] = sc[t] - deg;                  // local exclusive offset
    const int id = (b << 8) + t;
    if (id < n) {
        rowptr[id] = sBase + loc[t];
        dinv[id]   = rsqrtf((float)(deg + 1));   // +1 self-loop
    }
    h[t] = 0;                              // per-dst cursor
    __syncthreads();
    unsigned* __restrict__ outp = erec + sBase;
    for (int i = t; i < cb; i += 256) {
        const unsigned r  = eb[i];
        const int      lb = r >> 24;
        const int      p  = atomicAdd(&h[lb], 1);
        outp[loc[lb] + p] = r & 0xFFFFFFu;
    }
}

// xs[row] = dinv[row] * f16(x[row]) for row<n; xs[n] = 0 (tail-pad row);
// also zeroes h2s row n.  8 elems/thread.
__global__ __launch_bounds__(256) void k_scale(const float* __restrict__ x,
                                               const float* __restrict__ dinv,
                                               unsigned short* __restrict__ xs,
                                               unsigned short* __restrict__ h2s,
                                               int n) {
    const int gid = blockIdx.x * 256 + threadIdx.x;
    const int i8  = gid * 8;
    const int row = i8 >> 7;
    if (row < n) {
        const float wd = dinv[row];
        float4 v0 = *(const float4*)&x[i8];
        float4 v1 = *(const float4*)&x[i8 + 4];
        uint4 o;
        o.x = pkh(v0.x * wd, v0.y * wd); o.y = pkh(v0.z * wd, v0.w * wd);
        o.z = pkh(v1.x * wd, v1.y * wd); o.w = pkh(v1.z * wd, v1.w * wd);
        *(uint4*)&xs[i8] = o;
    } else if (row == n) {
        *(uint4*)&xs[i8] = make_uint4(0, 0, 0, 0);
        const int k = gid - n * 16;                  // 0..15
        if (k < 8) *(uint4*)&h2s[(size_t)n * 64 + k * 8] = make_uint4(0, 0, 0, 0);
    }
}

// ---------------------------------------------------------------------------
// Fused layer-1 + W2 commute.  16 rows/block, 256 thr (4 waves).
// Phase A: register gather, 16 lanes/row, lane b owns feats [8b,8b+8) (one
//          uint4 = 16B per row per lane); DEPTH-8 branch-free edge pipeline
//          (8 named uint4 in flight, 8 record prefetches); uniform coef wd.
//          -> f16 into swizzled LDS sM[16][128] (linear [row][feat]).
// Phase B: MFMA (agg)@W1: wave w owns cols [32w,32w+32); single M-tile;
//          A-frags from LDS (b128, XOR-16 swizzle), B-frags from Wpk1.
// Phase C: +b1, relu, write a1 back into the same LDS tile (f16, same swizzle).
// Phase D: MFMA a1@W2 -> cols [16w,16w+16), scale by dinv[row] -> h2s.
// LDS swizzle: byte ^= (row&7)<<4 applied to final address (write & read).
// ---------------------------------------------------------------------------
__global__ __launch_bounds__(256, 4) void fused_l1(const unsigned short* __restrict__ Xs,
                                                   const unsigned short* __restrict__ Wpk1,
                                                   const float* __restrict__ bias1,
                                                   const unsigned short* __restrict__ Wpk2,
                                                   const int* __restrict__ rowptr,
                                                   const unsigned* __restrict__ erec,
                                                   const float* __restrict__ dinv,
                                                   unsigned short* __restrict__ h2s,
                                                   int n) {
    __shared__ __align__(16) char sMb[RPB1 * 256];   // 16 rows x 128 f16 = 4 KB

    const int t    = threadIdx.x;
    const int row0 = blockIdx.x * RPB1;

    // ---- Phase A: gather ----
    {
        const int r = t >> 4;                 // row-in-block 0..15
        const int b = t & 15;                 // lane-in-row  0..15 (8 feats each)
        const int d = row0 + r;
        float ga[8] = {};
        if (d < n) {
            const float wd = dinv[d];
            {
                uint4 u = *((const uint4*)(Xs + ((size_t)d << 7)) + b);
                acc8h(ga, wd, u);             // self term: wd*xs[d] = wd^2*x[d]
            }
            const int beg = rowptr[d], end = rowptr[d + 1];
            int j = beg;
            const unsigned Z = (unsigned)n;   // zero row for tail slots
            if (j < end) {
                unsigned s0 = (j     < end) ? erec[j]     : Z;
                unsigned s1 = (j + 1 < end) ? erec[j + 1] : Z;
                unsigned s2 = (j + 2 < end) ? erec[j + 2] : Z;
                unsigned s3 = (j + 3 < end) ? erec[j + 3] : Z;
                unsigned s4 = (j + 4 < end) ? erec[j + 4] : Z;
                unsigned s5 = (j + 5 < end) ? erec[j + 5] : Z;
                unsigned s6 = (j + 6 < end) ? erec[j + 6] : Z;
                unsigned s7 = (j + 7 < end) ? erec[j + 7] : Z;
                while (j < end) {
                    // issue 8 row loads from current records
                    uint4 u0 = *((const uint4*)(Xs + ((size_t)s0 << 7)) + b);
                    uint4 u1 = *((const uint4*)(Xs + ((size_t)s1 << 7)) + b);
                    uint4 u2 = *((const uint4*)(Xs + ((size_t)s2 << 7)) + b);
                    uint4 u3 = *((const uint4*)(Xs + ((size_t)s3 << 7)) + b);
                    uint4 u4 = *((const uint4*)(Xs + ((size_t)s4 << 7)) + b);
                    uint4 u5 = *((const uint4*)(Xs + ((size_t)s5 << 7)) + b);
                    uint4 u6 = *((const uint4*)(Xs + ((size_t)s6 << 7)) + b);
                    uint4 u7 = *((const uint4*)(Xs + ((size_t)s7 << 7)) + b);
                    const int jn = j + 8;
                    s0 = (jn     < end) ? erec[jn]     : Z;   // prefetch next oct
                    s1 = (jn + 1 < end) ? erec[jn + 1] : Z;
                    s2 = (jn + 2 < end) ? erec[jn + 2] : Z;
                    s3 = (jn + 3 < end) ? erec[jn + 3] : Z;
                    s4 = (jn + 4 < end) ? erec[jn + 4] : Z;
                    s5 = (jn + 5 < end) ? erec[jn + 5] : Z;
                    s6 = (jn + 6 < end) ? erec[jn + 6] : Z;
                    s7 = (jn + 7 < end) ? erec[jn + 7] : Z;
                    acc8h(ga, wd, u0);        // uniform coef; zero row kills tail
                    acc8h(ga, wd, u1);
                    acc8h(ga, wd, u2);
                    acc8h(ga, wd, u3);
                    acc8h(ga, wd, u4);
                    acc8h(ga, wd, u5);
                    acc8h(ga, wd, u6);
                    acc8h(ga, wd, u7);
                    j = jn;
                }
            }
        }
        uint4 o;
        o.x = pkh(ga[0], ga[1]); o.y = pkh(ga[2], ga[3]);
        o.z = pkh(ga[4], ga[5]); o.w = pkh(ga[6], ga[7]);
        const int swz = (r & 7) << 4;
        *(uint4*)(sMb + ((r * 256 + b * 16) ^ swz)) = o;   // feats [8b,8b+8)
    }
    __syncthreads();

    const int w  = t >> 6;                    // wave 0..3
    const int l  = t & 63;
    const int lr = l & 15;                    // frag row/col within 16-tile
    const int lk = (l >> 4) << 4;             // byte offset of this lane's k-octet
    const int sz = (lr & 7) << 4;             // swizzle for row lr

    // ---- Phase B: agg@W1, wave w -> cols [32w, 32w+32) ----
    f4v acc[2] = {};
#pragma unroll
    for (int kt = 0; kt < 4; ++kt) {
        const int kb = kt * 64 + lk;
        h8 a0 = *(const h8*)(sMb + ((lr * 256 + kb) ^ sz));
        const h8* Bp = (const h8*)Wpk1 + (kt * 8 + w * 2) * 64 + l;
        h8 b0 = Bp[0];
        h8 b1 = Bp[64];
        acc[0] = __builtin_amdgcn_mfma_f32_16x16x32_f16(a0, b0, acc[0], 0, 0, 0);
        acc[1] = __builtin_amdgcn_mfma_f32_16x16x32_f16(a0, b1, acc[1], 0, 0, 0);
    }
    __syncthreads();                          // all sM reads done before a1 overwrite

    // ---- Phase C: bias+relu -> a1 (f16) back into the same LDS tile ----
    {
        const float bb0 = bias1[w * 32 + lr];
        const float bb1 = bias1[w * 32 + 16 + lr];
        const int c0 = (w * 32 + lr) * 2;
        const int c1 = (w * 32 + 16 + lr) * 2;
#pragma unroll
        for (int v = 0; v < 4; ++v) {
            const int row = ((l >> 4) << 2) + v;          // 0..15
            const int rs  = (row & 7) << 4;
            float o0 = fmaxf(acc[0][v] + bb0, 0.f);
            float o1 = fmaxf(acc[1][v] + bb1, 0.f);
            *(_Float16*)(sMb + ((row * 256 + c0) ^ rs)) = (_Float16)o0;
            *(_Float16*)(sMb + ((row * 256 + c1) ^ rs)) = (_Float16)o1;
        }
    }
    __syncthreads();

    // ---- Phase D: a1@W2 -> h2s (scaled by dinv[row]), wave w -> cols [16w,16w+16) ----
    f4v acc2 = {};
#pragma unroll
    for (int kt = 0; kt < 4; ++kt) {
        const int kb = kt * 64 + lk;
        h8 a0 = *(const h8*)(sMb + ((lr * 256 + kb) ^ sz));
        h8 b  = *((const h8*)Wpk2 + (kt * 4 + w) * 64 + l);
        acc2 = __builtin_amdgcn_mfma_f32_16x16x32_f16(a0, b, acc2, 0, 0, 0);
    }
#pragma unroll
    for (int v = 0; v < 4; ++v) {
        const int row = row0 + ((l >> 4) << 2) + v;
        if (row < n) {
            _Float16 hv = (_Float16)(acc2[v] * dinv[row]);
            h2s[(size_t)row * 64 + w * 16 + lr] = __builtin_bit_cast(unsigned short, hv);
        }
    }
}

// ---------------------------------------------------------------------------
// Layer-2 aggregation: out[d] = wd*(h2s[d] + sum_e h2s[src_e]) + b2, wd=dinv[d].
// Pure 64-wide gather (128 B/row): 8 lanes/row, 1 uint4 (8 f16) per lane;
// DEPTH-8 edge pipeline (8 named uint4 in flight).  (256,4): loose bounds so
// the allocator can keep ~75 VGPR live without spilling (rounds 4/6 lesson).
// ---------------------------------------------------------------------------
__global__ __launch_bounds__(256, 4) void k_out(const unsigned short* __restrict__ h2s,
                                                const float* __restrict__ b2,
                                                const int* __restrict__ rowptr,
                                                const unsigned* __restrict__ erec,
                                                const float* __restrict__ dinv,
                                                float* __restrict__ out, int n) {
    const int t = threadIdx.x;
    const int r = t >> 3;
    const int b = t & 7;
    const int d = blockIdx.x * RPBO + r;
    if (d >= n) return;

    const float wd = dinv[d];
    float ga[8] = {};
    {
        uint4 u = *((const uint4*)(h2s + ((size_t)d << 6)) + b);
        acc8h(ga, wd, u);                     // self term
    }
    const int beg = rowptr[d], end = rowptr[d + 1];
    int j = beg;
    const unsigned Z = (unsigned)n;
    if (j < end) {
        unsigned s0 = (j     < end) ? erec[j]     : Z;
        unsigned s1 = (j + 1 < end) ? erec[j + 1] : Z;
        unsigned s2 = (j + 2 < end) ? erec[j + 2] : Z;
        unsigned s3 = (j + 3 < end) ? erec[j + 3] : Z;
        unsigned s4 = (j + 4 < end) ? erec[j + 4] : Z;
        unsigned s5 = (j + 5 < end) ? erec[j + 5] : Z;
        unsigned s6 = (j + 6 < end) ? erec[j + 6] : Z;
        unsigned s7 = (j + 7 < end) ? erec[j + 7] : Z;
        while (j < end) {
            uint4 u0 = *((const uint4*)(h2s + ((size_t)s0 << 6)) + b);
            uint4 u1 = *((const uint4*)(h2s + ((size_t)s1 << 6)) + b);
            uint4 u2 = *((const uint4*)(h2s + ((size_t)s2 << 6)) + b);
            uint4 u3 = *((const uint4*)(h2s + ((size_t)s3 << 6)) + b);
            uint4 u4 = *((const uint4*)(h2s + ((size_t)s4 << 6)) + b);
            uint4 u5 = *((const uint4*)(h2s + ((size_t)s5 << 6)) + b);
            uint4 u6 = *((const uint4*)(h2s + ((size_t)s6 << 6)) + b);
            uint4 u7 = *((const uint4*)(h2s + ((size_t)s7 << 6)) + b);
            const int jn = j + 8;
            s0 = (jn     < end) ? erec[jn]     : Z;
            s1 = (jn + 1 < end) ? erec[jn + 1] : Z;
            s2 = (jn + 2 < end) ? erec[jn + 2] : Z;
            s3 = (jn + 3 < end) ? erec[jn + 3] : Z;
            s4 = (jn + 4 < end) ? erec[jn + 4] : Z;
            s5 = (jn + 5 < end) ? erec[jn + 5] : Z;
            s6 = (jn + 6 < end) ? erec[jn + 6] : Z;
            s7 = (jn + 7 < end) ? erec[jn + 7] : Z;
            acc8h(ga, wd, u0);
            acc8h(ga, wd, u1);
            acc8h(ga, wd, u2);
            acc8h(ga, wd, u3);
            acc8h(ga, wd, u4);
            acc8h(ga, wd, u5);
            acc8h(ga, wd, u6);
            acc8h(ga, wd, u7);
            j = jn;
        }
    }
    const float4 bv0 = *(const float4*)&b2[b * 8];
    const float4 bv1 = *(const float4*)&b2[b * 8 + 4];
    float* O = out + (size_t)d * 64 + b * 8;
    *(float4*)O       = make_float4(ga[0] + bv0.x, ga[1] + bv0.y, ga[2] + bv0.z, ga[3] + bv0.w);
    *(float4*)(O + 4) = make_float4(ga[4] + bv1.x, ga[5] + bv1.y, ga[6] + bv1.z, ga[7] + bv1.w);
}

// ---------------------------------------------------------------------------

extern "C" void kernel_launch(void* const* d_in, const int* in_sizes, int n_in,
                              void* d_out, int out_size, void* d_ws, size_t ws_size,
                              hipStream_t stream) {
    const float* x  = (const float*)d_in[0];
    const int*   ei = (const int*)d_in[1];
    const float* W1 = (const float*)d_in[2];
    const float* b1 = (const float*)d_in[3];
    const float* W2 = (const float*)d_in[4];
    const float* b2 = (const float*)d_in[5];
    float* out = (float*)d_out;

    const int N = in_sizes[0] / 128;
    const int E = in_sizes[1] / 2;
    const int* src = ei;
    const int* dst = ei + E;
    const int NBK = (N + 255) >> 8;        // 196 for N=50000
    if (NBK > 256) return;                 // design limit (N <= 65536; src fits 24b)

    // workspace carve (256B aligned)
    size_t off = 0;
    char* base = (char*)d_ws;
    auto carve = [&](size_t bytes) -> void* {
        void* p = base + off;
        off += (bytes + 255) & ~(size_t)255;
        return p;
    };
    int*      bcur   = (int*)carve(256 * 4);               // zeroed per call
    int*      rowptr = (int*)carve((size_t)(N + 1) * 4);
    float*    dinv   = (float*)carve((size_t)N * 4);
    unsigned* erec   = (unsigned*)carve((size_t)E * 4);
    unsigned* ebuf   = (unsigned*)carve((size_t)256 * CAP * 4);  // bucket staging 8.4MB
    unsigned short* xs   = (unsigned short*)carve((size_t)(N + 1) * 128 * 2);
    unsigned short* h2s  = (unsigned short*)carve((size_t)(N + 1) * 64 * 2);
    unsigned short* Wpk1 = (unsigned short*)carve(128 * 128 * 2);
    unsigned short* Wpk2 = (unsigned short*)carve(128 * 64 * 2);

    if (off > ws_size) return;  // diagnostic guard

    // 1) bucket phase A + W frag-pack (one launch); per-bucket sort; row scale
    const int EPB = (E + PA_BLK - 1) / PA_BLK;
    hipMemsetAsync(bcur, 0, 256 * 4, stream);
    k_prep<<<PA_BLK + 12, 256, 0, stream>>>(src, dst, E, bcur, ebuf, EPB,
                                            W1, W2, Wpk1, Wpk2);
    k_bucket<<<NBK, 256, 0, stream>>>(ebuf, bcur, rowptr, dinv, erec, N, NBK, E);
    k_scale<<<((N + 1) * 16 + 255) / 256, 256, 0, stream>>>(x, dinv, xs, h2s, N);

    // 2) fused layer 1 (+W2 commute): h2s = dinv .* (relu(agg@W1 + b1) @ W2)
    fused_l1<<<(N + RPB1 - 1) / RPB1, 256, 0, stream>>>(xs, Wpk1, b1, Wpk2,
                                                        rowptr, erec, dinv, h2s, N);
    // 3) layer 2 aggregation: out = wd*(agg h2s) + b2   (fp32 out)
    k_out<<<(N + RPBO - 1) / RPBO, 256, 0, stream>>>(h2s, b2, rowptr, erec, dinv, out, N);
}